// Round 2
// baseline (743.186 us; speedup 1.0000x reference)
//
#include <hip/hip_runtime.h>

#define B_SZ   4096
#define D_SZ   128
#define K_SZ   256
#define NBUCK  4096      // bucket = idx >> 8; idx < 1e6 -> bucket < 3907
#define BCAP   1024      // slots/bucket; expected ~268, P(overflow) ~ 0

constexpr float INV_T    = 1.0f / 0.07f;
constexpr float NOISE    = 255.0f / 1000000.0f;   // (K-1)/N
constexpr float EPS_C    = 1e-7f;
constexpr float K_OVER_N = 256.0f / 1000000.0f;   // K/N

// ---------------------------------------------------------------------------
// Workspace layout (poisoned every iteration by the harness -> must re-init):
//   [0,            16 KB)  bucket counters   (NBUCK * 4 B)
//   [16 KB,   +32 MB)      bucket entries    (NBUCK * BCAP * 8 B)
//   [ ... ,   + 4 MB)      esims[B*K]        exp(logit) scattered by kernel B
//   [ ... ,   +16 KB)      partial[B]        per-row loss partials
// ---------------------------------------------------------------------------

__global__ __launch_bounds__(256) void zero_counters(int* __restrict__ cnt)
{
    const int i = blockIdx.x * 256 + threadIdx.x;
    if (i < NBUCK) cnt[i] = 0;
}

// Scatter the 1.05M samples into 128KB-region buckets. entry = (row<<32)|i,
// where i = b*256+k is both the sample id and the esims index.
__global__ __launch_bounds__(256, 8) void bin_samples(
    const int* __restrict__ targets,
    const int* __restrict__ indices,
    int*                 __restrict__ cnt,
    unsigned long long*  __restrict__ ent)
{
    const int i = blockIdx.x * 256 + threadIdx.x;   // i < B*K
    const int b = i >> 8;
    const int k = i & (K_SZ - 1);
    const int row = (k == 0) ? targets[b] : indices[i];
    const int bu  = row >> 8;
    const int slot = atomicAdd(&cnt[bu], 1);
    if (slot < BCAP)
        ent[(size_t)bu * BCAP + slot] =
            ((unsigned long long)(unsigned)row << 32) | (unsigned)i;
}

// One block per bucket. All row reads of a block land in one 128KB region of
// `memory` -> DRAM row locality instead of fully-random 512B granules.
// 8 lanes per entry: lane s loads float4 slots {s, s+8, s+16, s+24} of the
// row (fully coalesced 128B per group-chunk), dot vs x[b] (L2-resident, 2MB),
// 3-stage shfl reduce, scatter exp(logit) to esims[i].
__global__ __launch_bounds__(256, 4) void gather_dot(
    const float* __restrict__ x,        // [B, D]
    const float* __restrict__ memory,   // [N, D]
    const int*                __restrict__ cnt,
    const unsigned long long* __restrict__ ent,
    float*       __restrict__ esims)    // [B*K]
{
    const int bu = blockIdx.x;
    const int nb = min(cnt[bu], BCAP);
    if (nb == 0) return;

    const int tid = threadIdx.x;
    const int g   = tid >> 3;    // entry group 0..31 within block
    const int s   = tid & 7;     // float4 slot within 128B chunk

    for (int base = 0; base < nb; base += 32) {
        const int e  = base + g;
        const int ec = min(e, nb - 1);
        const unsigned long long pk = ent[(size_t)bu * BCAP + ec];
        const int i   = (int)(pk & 0xffffffffu);
        const int row = (int)(pk >> 32);

        const float4* __restrict__ rp =
            (const float4*)(memory + (size_t)row * D_SZ);
        const float4* __restrict__ xp =
            (const float4*)(x + (size_t)(i >> 8) * D_SZ);

        // 8 independent loads per lane; all lanes/groups independent.
        const float4 r0 = rp[0 * 8 + s];
        const float4 r1 = rp[1 * 8 + s];
        const float4 r2 = rp[2 * 8 + s];
        const float4 r3 = rp[3 * 8 + s];
        const float4 x0 = xp[0 * 8 + s];
        const float4 x1 = xp[1 * 8 + s];
        const float4 x2 = xp[2 * 8 + s];
        const float4 x3 = xp[3 * 8 + s];

        float a0 = 0.f, a1 = 0.f;
        a0 = fmaf(r0.x, x0.x, fmaf(r0.y, x0.y, fmaf(r0.z, x0.z, fmaf(r0.w, x0.w, a0))));
        a1 = fmaf(r1.x, x1.x, fmaf(r1.y, x1.y, fmaf(r1.z, x1.z, fmaf(r1.w, x1.w, a1))));
        a0 = fmaf(r2.x, x2.x, fmaf(r2.y, x2.y, fmaf(r2.z, x2.z, fmaf(r2.w, x2.w, a0))));
        a1 = fmaf(r3.x, x3.x, fmaf(r3.y, x3.y, fmaf(r3.z, x3.z, fmaf(r3.w, x3.w, a1))));
        float p = a0 + a1;

        // reduce across the 8-lane group (masks 1,2,4 stay in-group)
        p += __shfl_xor(p, 1, 64);
        p += __shfl_xor(p, 2, 64);
        p += __shfl_xor(p, 4, 64);

        if (s == 0 && e < nb)
            esims[i] = expf(p * INV_T);
    }
}

// Per batch-row softmax-denominator + NCE loss terms (same tail as before).
__global__ __launch_bounds__(256, 8) void reduce_loss(
    const float* __restrict__ esims,    // [B*K]
    float*       __restrict__ partial)  // [B]
{
    __shared__ float s_red[4];
    const int b    = blockIdx.x;
    const int tid  = threadIdx.x;
    const int lane = tid & 63;
    const int wave = tid >> 6;

    const float e = esims[(size_t)b * K_SZ + tid];

    float sum = e;
    #pragma unroll
    for (int m = 32; m >= 1; m >>= 1)
        sum += __shfl_xor(sum, m, 64);
    if (lane == 0) s_red[wave] = sum;
    __syncthreads();
    const float S = s_red[0] + s_red[1] + s_red[2] + s_red[3];

    const float sims = e * (K_OVER_N / S);
    float term = (tid == 0)
        ? logf(sims / (sims + NOISE + EPS_C))    // lnPmt (positive)
        : logf(NOISE / (sims + NOISE + EPS_C));  // lnPon (noise)

    #pragma unroll
    for (int m = 32; m >= 1; m >>= 1)
        term += __shfl_xor(term, m, 64);
    __syncthreads();
    if (lane == 0) s_red[wave] = term;
    __syncthreads();
    if (tid == 0)
        partial[b] = s_red[0] + s_red[1] + s_red[2] + s_red[3];
}

__global__ __launch_bounds__(256) void nce_final(
    const float* __restrict__ partial, float* __restrict__ out)
{
    const int tid = threadIdx.x;
    float s = 0.0f;
    #pragma unroll
    for (int i = tid; i < B_SZ; i += 256)
        s += partial[i];
    #pragma unroll
    for (int m = 32; m >= 1; m >>= 1)
        s += __shfl_xor(s, m, 64);
    __shared__ float sr[4];
    if ((tid & 63) == 0) sr[tid >> 6] = s;
    __syncthreads();
    if (tid == 0)
        out[0] = -(sr[0] + sr[1] + sr[2] + sr[3]) / (float)B_SZ;
}

extern "C" void kernel_launch(void* const* d_in, const int* in_sizes, int n_in,
                              void* d_out, int out_size, void* d_ws, size_t ws_size,
                              hipStream_t stream) {
    const float* x       = (const float*)d_in[0];
    const int*   targets = (const int*)  d_in[1];
    const float* memory  = (const float*)d_in[2];
    const int*   indices = (const int*)  d_in[3];
    float* out = (float*)d_out;

    char* ws = (char*)d_ws;
    int*                cnt     = (int*)ws;                         // 16 KB
    unsigned long long* ent     = (unsigned long long*)(ws + 16384);
    float*              esims   = (float*)(ws + 16384 + (size_t)NBUCK * BCAP * 8);
    float*              partial = esims + (size_t)B_SZ * K_SZ;

    zero_counters<<<NBUCK / 256, 256, 0, stream>>>(cnt);
    bin_samples<<<(B_SZ * K_SZ) / 256, 256, 0, stream>>>(targets, indices, cnt, ent);
    gather_dot<<<NBUCK, 256, 0, stream>>>(x, memory, cnt, ent, esims);
    reduce_loss<<<B_SZ, 256, 0, stream>>>(esims, partial);
    nce_final<<<1, 256, 0, stream>>>(partial, out);
}